// Round 4
// baseline (1270.838 us; speedup 1.0000x reference)
//
#include <hip/hip_runtime.h>
#include <math.h>

#define NUSERS 50000
#define NITEMS 50000
#define NTOT   100000
#define NNODE  50000      // per direction
#define NCHUNK 196        // ceil(50000/256)
#define MTILES 6250       // 100000/16 row tiles
#define KDIM   512

typedef __attribute__((ext_vector_type(4))) float f32x4;
typedef __attribute__((ext_vector_type(8))) short short8;
typedef unsigned int u32;

#define AS1 __attribute__((address_space(1)))
#define AS3 __attribute__((address_space(3)))

static __device__ __forceinline__ unsigned short f2bf(float f) {
  unsigned int u = __float_as_uint(f);
  u += 0x7fffu + ((u >> 16) & 1u);
  return (unsigned short)(u >> 16);
}

static __device__ __forceinline__ u32 pack2(float x, float y) {
  return (u32)f2bf(x) | ((u32)f2bf(y) << 16);
}

static __device__ __forceinline__ void gload_lds16(const void* g, void* l) {
  __builtin_amdgcn_global_load_lds((const AS1 u32*)g, (AS3 u32*)l, 16, 0, 0);
}

// ---------------- pack W'' into MFMA B-fragment order -----------------
__global__ void pack_w_kernel(const float* __restrict__ w_ih,
                              const float* __restrict__ w_hh,
                              const float* __restrict__ b_ih,
                              const float* __restrict__ b_hh,
                              unsigned short* __restrict__ Wb,
                              float* __restrict__ bb) {
  int idx = blockIdx.x * 256 + threadIdx.x;       // 0 .. 512*512-1
  int j = idx & 7, l = (idx >> 3) & 63, ktt = idx >> 9;
  int kt = ktt & 15, tt = ktt >> 4;
  int g = tt * 16 + (l & 15);
  int k = kt * 32 + (l >> 4) * 8 + j;
  float v;
  if (g < 256)      v = (k < 384) ? w_ih[g * 384 + k] : w_hh[g * 128 + (k - 384)];
  else if (g < 384) v = (k < 384) ? w_ih[g * 384 + k] : 0.0f;
  else              v = (k < 384) ? 0.0f : w_hh[(g - 128) * 128 + (k - 384)];
  Wb[idx] = f2bf(v);
  if (idx < 512) {
    float b = (idx < 256) ? (b_ih[idx] + b_hh[idx])
            : (idx < 384) ? b_ih[idx]
                          : b_hh[idx - 128];
    bb[idx] = b;
  }
}

// ---------------- bf16 pre-cast of gathered memory rows -----------------
// si / si_r (the arrays gathered by src index) -> bf16, 256B rows
__global__ void cast_mem_kernel(const float* __restrict__ si,
                                const float* __restrict__ si_r,
                                unsigned short* __restrict__ si_b,
                                unsigned short* __restrict__ sir_b) {
  int i = blockIdx.x * 256 + threadIdx.x;          // 0 .. 1,599,999 (8 floats each)
  const float* src; unsigned short* dst; int off;
  if (i < 800000) { src = si;   dst = si_b;  off = i; }
  else            { src = si_r; dst = sir_b; off = i - 800000; }
  const f32x4* p = (const f32x4*)(src + (size_t)off * 8);
  f32x4 a = p[0], b = p[1];
  short8 o;
  o[0] = f2bf(a[0]); o[1] = f2bf(a[1]); o[2] = f2bf(a[2]); o[3] = f2bf(a[3]);
  o[4] = f2bf(b[0]); o[5] = f2bf(b[1]); o[6] = f2bf(b[2]); o[7] = f2bf(b[3]);
  *(short8*)(dst + (size_t)off * 8) = o;
}

// ---------------- CSR build -----------------
__global__ void hist_kernel(const int* __restrict__ dst_g,
                            const int* __restrict__ dst_gr,
                            int* __restrict__ deg_j, int* __restrict__ deg_i, int E) {
  int i = blockIdx.x * 256 + threadIdx.x;
  if (i < E) atomicAdd(&deg_j[dst_g[i]], 1);
  else if (i < 2 * E) atomicAdd(&deg_i[dst_gr[i - E]], 1);
}

__global__ void chunksum_kernel(const int* __restrict__ deg_j,
                                const int* __restrict__ deg_i,
                                int* __restrict__ csum) {
  int c = blockIdx.x;                    // 0..2*NCHUNK-1
  const int* deg = (c < NCHUNK) ? deg_j : deg_i;
  int cc = (c < NCHUNK) ? c : c - NCHUNK;
  int t = threadIdx.x;
  int idx = cc * 256 + t;
  int v = (idx < NNODE) ? deg[idx] : 0;
  for (int off = 32; off; off >>= 1) v += __shfl_down(v, off, 64);
  __shared__ int wsum[4];
  if ((t & 63) == 0) wsum[t >> 6] = v;
  __syncthreads();
  if (t == 0) csum[c] = wsum[0] + wsum[1] + wsum[2] + wsum[3];
}

__global__ void chunkscan_kernel(const int* __restrict__ csum, int* __restrict__ coff) {
  int d = blockIdx.x;                    // 0 or 1
  const int* cs = csum + d * NCHUNK;
  int* co = coff + d * NCHUNK;
  int t = threadIdx.x, lane = t & 63, w = t >> 6;
  int v = (t < NCHUNK) ? cs[t] : 0;
  int x = v;
  for (int off = 1; off < 64; off <<= 1) {
    int y = __shfl_up(x, off, 64);
    if (lane >= off) x += y;
  }
  __shared__ int wt[4];
  if (lane == 63) wt[w] = x;
  __syncthreads();
  int add = 0;
  for (int k = 0; k < 4; ++k) if (k < w) add += wt[k];
  if (t < NCHUNK) co[t] = add + x - v;   // exclusive prefix
}

__global__ void localscan_kernel(const int* __restrict__ deg_j,
                                 const int* __restrict__ deg_i,
                                 const int* __restrict__ coff,
                                 int* __restrict__ rs_j, int* __restrict__ cur_j,
                                 int* __restrict__ rs_i, int* __restrict__ cur_i) {
  int c = blockIdx.x;
  bool dj = c < NCHUNK;
  const int* deg = dj ? deg_j : deg_i;
  int cc = dj ? c : c - NCHUNK;
  int* rs = dj ? rs_j : rs_i;
  int* cur = dj ? cur_j : cur_i;
  int base = coff[c];
  int t = threadIdx.x, lane = t & 63, w = t >> 6;
  int idx = cc * 256 + t;
  int v = (idx < NNODE) ? deg[idx] : 0;
  int x = v;
  for (int off = 1; off < 64; off <<= 1) {
    int y = __shfl_up(x, off, 64);
    if (lane >= off) x += y;
  }
  __shared__ int wt[4];
  if (lane == 63) wt[w] = x;
  __syncthreads();
  int add = 0;
  for (int k = 0; k < 4; ++k) if (k < w) add += wt[k];
  int ex = base + add + x - v;
  if (idx < NNODE) { rs[idx] = ex; cur[idx] = ex; }
}

// fill: one 16B record per edge: (src, eid, ts_bits, 0)
__global__ void fill_kernel(const int* __restrict__ src_g, const int* __restrict__ dst_g,
                            const float* __restrict__ t,
                            const int* __restrict__ src_gr, const int* __restrict__ dst_gr,
                            const float* __restrict__ t_r,
                            int* __restrict__ cur_j, int* __restrict__ cur_i,
                            int4* __restrict__ recP_j, int4* __restrict__ recP_i,
                            int E) {
  int i = blockIdx.x * 256 + threadIdx.x;
  if (i < E) {
    int pos = atomicAdd(&cur_j[dst_g[i]], 1);
    recP_j[pos] = make_int4(src_g[i], i, __float_as_int(t[i]), 0);
  } else if (i < 2 * E) {
    int k = i - E;
    int pos = atomicAdd(&cur_i[dst_gr[k]], 1);
    recP_i[pos] = make_int4(src_gr[k], k, __float_as_int(t_r[k]), 0);
  }
}

// ---------------- gather: mean-message + pack X row in A-fragment order ----------------
// packed k layout: [0,128)=mean src_mem, [128,256)=h*(deg>0), [256,320)=mean tenc,
// [320,384)=mean edge feat, [384,512)=h
__global__ __launch_bounds__(256) void gather_kernel(
    const unsigned short* __restrict__ si_b, const unsigned short* __restrict__ sir_b,
    const float* __restrict__ sj, const float* __restrict__ sj_r,
    const float* __restrict__ e, const float* __restrict__ e_r,
    const int* __restrict__ rs_j, const int* __restrict__ rs_i,
    const int* __restrict__ deg_j, const int* __restrict__ deg_i,
    const int4* __restrict__ recP_j, const int4* __restrict__ recP_i,
    unsigned short* __restrict__ Xb) {
  __shared__ __align__(16) unsigned short rowbuf[4][512];
  int wid = threadIdx.x >> 6, lane = threadIdx.x & 63;
  int node = blockIdx.x * 4 + wid;                 // 0..99999
  bool user = node < NUSERS;
  int idx = user ? node : node - NUSERS;
  const unsigned short* smem = user ? sir_b : si_b;   // bf16 rows, 128 shorts
  const float* h    = user ? sj_r : sj;
  const float* ef   = user ? e_r : e;
  int start = __builtin_amdgcn_readfirstlane((user ? rs_i : rs_j)[idx]);
  int deg   = __builtin_amdgcn_readfirstlane((user ? deg_i : deg_j)[idx]);
  const int4* rec = user ? recP_i : recP_j;

  // freq[lane] = 10^(-9*lane/63) = exp(-lane * 9/63 * ln 10)
  float freq = __expf((float)lane * -0.3289407276f);
  // h row: issue early, consumed only in the epilogue
  float2 hvf = *(const float2*)(h + (size_t)idx * 128 + 2 * lane);

  float asx = 0.f, asy = 0.f;   // mean src_mem, k = 2*lane, 2*lane+1
  float at  = 0.f;              // tenc, k = 256+lane
  float ae  = 0.f;              // edge feat, k = 320+lane

  for (int base = 0; base < deg; base += 64) {
    int nn = deg - base; if (nn > 64) nn = 64;
    // cooperative record load: lane l holds record base+l (clamped)
    int cl = (lane < nn) ? base + lane : base + nn - 1;
    int4 r = rec[start + cl];
    for (int j0 = 0; j0 < nn; j0 += 8) {
      int j1 = (j0 + 1 < nn) ? j0 + 1 : nn - 1;
      int j2 = (j0 + 2 < nn) ? j0 + 2 : nn - 1;
      int j3 = (j0 + 3 < nn) ? j0 + 3 : nn - 1;
      int j4 = (j0 + 4 < nn) ? j0 + 4 : nn - 1;
      int j5 = (j0 + 5 < nn) ? j0 + 5 : nn - 1;
      int j6 = (j0 + 6 < nn) ? j0 + 6 : nn - 1;
      int j7 = (j0 + 7 < nn) ? j0 + 7 : nn - 1;
      float w1 = (j0 + 1 < nn) ? 1.0f : 0.0f;
      float w2 = (j0 + 2 < nn) ? 1.0f : 0.0f;
      float w3 = (j0 + 3 < nn) ? 1.0f : 0.0f;
      float w4 = (j0 + 4 < nn) ? 1.0f : 0.0f;
      float w5 = (j0 + 5 < nn) ? 1.0f : 0.0f;
      float w6 = (j0 + 6 < nn) ? 1.0f : 0.0f;
      float w7 = (j0 + 7 < nn) ? 1.0f : 0.0f;

      int s0 = __builtin_amdgcn_readlane(r.x, j0), e0 = __builtin_amdgcn_readlane(r.y, j0);
      int s1 = __builtin_amdgcn_readlane(r.x, j1), e1 = __builtin_amdgcn_readlane(r.y, j1);
      int s2 = __builtin_amdgcn_readlane(r.x, j2), e2 = __builtin_amdgcn_readlane(r.y, j2);
      int s3 = __builtin_amdgcn_readlane(r.x, j3), e3 = __builtin_amdgcn_readlane(r.y, j3);
      int s4 = __builtin_amdgcn_readlane(r.x, j4), e4 = __builtin_amdgcn_readlane(r.y, j4);
      int s5 = __builtin_amdgcn_readlane(r.x, j5), e5 = __builtin_amdgcn_readlane(r.y, j5);
      int s6 = __builtin_amdgcn_readlane(r.x, j6), e6 = __builtin_amdgcn_readlane(r.y, j6);
      int s7 = __builtin_amdgcn_readlane(r.x, j7), e7 = __builtin_amdgcn_readlane(r.y, j7);

      u32 v0 = *(const u32*)(smem + ((size_t)s0 << 7) + 2 * lane);
      u32 v1 = *(const u32*)(smem + ((size_t)s1 << 7) + 2 * lane);
      u32 v2 = *(const u32*)(smem + ((size_t)s2 << 7) + 2 * lane);
      u32 v3 = *(const u32*)(smem + ((size_t)s3 << 7) + 2 * lane);
      u32 v4 = *(const u32*)(smem + ((size_t)s4 << 7) + 2 * lane);
      u32 v5 = *(const u32*)(smem + ((size_t)s5 << 7) + 2 * lane);
      u32 v6 = *(const u32*)(smem + ((size_t)s6 << 7) + 2 * lane);
      u32 v7 = *(const u32*)(smem + ((size_t)s7 << 7) + 2 * lane);
      float f0 = ef[((size_t)e0 << 6) + lane];
      float f1 = ef[((size_t)e1 << 6) + lane];
      float f2 = ef[((size_t)e2 << 6) + lane];
      float f3 = ef[((size_t)e3 << 6) + lane];
      float f4 = ef[((size_t)e4 << 6) + lane];
      float f5 = ef[((size_t)e5 << 6) + lane];
      float f6 = ef[((size_t)e6 << 6) + lane];
      float f7 = ef[((size_t)e7 << 6) + lane];

      float c0 = __cosf(__int_as_float(__builtin_amdgcn_readlane(r.z, j0)) * freq);
      float c1 = __cosf(__int_as_float(__builtin_amdgcn_readlane(r.z, j1)) * freq);
      float c2 = __cosf(__int_as_float(__builtin_amdgcn_readlane(r.z, j2)) * freq);
      float c3 = __cosf(__int_as_float(__builtin_amdgcn_readlane(r.z, j3)) * freq);
      float c4 = __cosf(__int_as_float(__builtin_amdgcn_readlane(r.z, j4)) * freq);
      float c5 = __cosf(__int_as_float(__builtin_amdgcn_readlane(r.z, j5)) * freq);
      float c6 = __cosf(__int_as_float(__builtin_amdgcn_readlane(r.z, j6)) * freq);
      float c7 = __cosf(__int_as_float(__builtin_amdgcn_readlane(r.z, j7)) * freq);

      // unpack bf16 pair and accumulate (weighted for clamped tail slots)
      float l0 = __uint_as_float(v0 << 16), g0 = __uint_as_float(v0 & 0xffff0000u);
      float l1 = __uint_as_float(v1 << 16), g1 = __uint_as_float(v1 & 0xffff0000u);
      float l2 = __uint_as_float(v2 << 16), g2 = __uint_as_float(v2 & 0xffff0000u);
      float l3 = __uint_as_float(v3 << 16), g3 = __uint_as_float(v3 & 0xffff0000u);
      float l4 = __uint_as_float(v4 << 16), g4 = __uint_as_float(v4 & 0xffff0000u);
      float l5 = __uint_as_float(v5 << 16), g5 = __uint_as_float(v5 & 0xffff0000u);
      float l6 = __uint_as_float(v6 << 16), g6 = __uint_as_float(v6 & 0xffff0000u);
      float l7 = __uint_as_float(v7 << 16), g7 = __uint_as_float(v7 & 0xffff0000u);

      asx += l0 + w1 * l1 + w2 * l2 + w3 * l3 + w4 * l4 + w5 * l5 + w6 * l6 + w7 * l7;
      asy += g0 + w1 * g1 + w2 * g2 + w3 * g3 + w4 * g4 + w5 * g5 + w6 * g6 + w7 * g7;
      at  += c0 + w1 * c1 + w2 * c2 + w3 * c3 + w4 * c4 + w5 * c5 + w6 * c6 + w7 * c7;
      ae  += f0 + w1 * f1 + w2 * f2 + w3 * f3 + w4 * f4 + w5 * f5 + w6 * f6 + w7 * f7;
    }
  }

  float invc = (deg > 0) ? 1.0f / (float)deg : 0.0f;
  float hz   = (deg > 0) ? 1.0f : 0.0f;

  unsigned short* rb = rowbuf[wid];
  u32* rb32 = (u32*)rb;
  rb32[lane]       = pack2(asx * invc, asy * invc);   // k = 2*lane,2*lane+1
  rb32[64 + lane]  = pack2(hvf.x * hz, hvf.y * hz);   // k = 128+2*lane
  rb[256 + lane]   = f2bf(at * invc);                 // k = 256+lane
  rb[320 + lane]   = f2bf(ae * invc);                 // k = 320+lane
  rb32[192 + lane] = pack2(hvf.x, hvf.y);             // k = 384+2*lane

  // wave-private LDS: compiler orders ds_write -> ds_read via lgkmcnt, no barrier
  // transpose-write in A-fragment order: lane owns k = lane*8 .. lane*8+8
  int rt = node >> 4, m = node & 15;
  int kt2 = lane >> 2, q2 = lane & 3;
  short8 vv = *(const short8*)(rb + lane * 8);
  *(short8*)(Xb + (((size_t)rt * 16 + kt2) * 64 + q2 * 16 + m) * 8) = vv;
}

// ---------------- GEMM (100000 x 512) @ W''^T with fused GRU epilogue ----------------
// Block: 8 mtiles x 512 cols, 8 waves = 2 m-groups x 4 col-groups. Wave: 4 mtiles x
// 128 gemm-cols (2 n-tiles per gate). Per phase (K=64): stage 64KB of W into LDS
// (all 32 tt x 2 kt; one 1KB frag-block per gload_lds), A-loads issued BEFORE the
// barrier so HBM latency drains together with the stage; then 16 ds_read_b128 +
// 64 MFMA (ds:MFMA = 1:4, B reused across 4 mtiles). LDS 64KB -> 2 blocks/CU
// (16 waves): one block's stage/barrier drain hides under the other's MFMA phase.
__global__ __launch_bounds__(512, 4) void gemm_gru_kernel(
    const unsigned short* __restrict__ Xb,
    const unsigned short* __restrict__ Wb,
    const float* __restrict__ bb,
    const float* __restrict__ sj_r,
    const float* __restrict__ sj,
    float* __restrict__ out) {
  __shared__ __align__(16) unsigned short sB[32768];   // 64 KB: [kt2][tt][512]
  int wid = threadIdx.x >> 6, lane = threadIdx.x & 63;
  int mg = wid >> 2, cg = wid & 3;
  int mbase = blockIdx.x * 8 + mg * 4;     // wave's first mtile
  int col16 = lane & 15, quad = lane >> 4;

  f32x4 acc[4][4][2];
#pragma unroll
  for (int mi = 0; mi < 4; ++mi)
#pragma unroll
    for (int g = 0; g < 4; ++g)
#pragma unroll
      for (int nt = 0; nt < 2; ++nt) acc[mi][g][nt] = (f32x4)0.0f;

  const unsigned short* Ap[4];
#pragma unroll
  for (int mi = 0; mi < 4; ++mi) {
    int mt = mbase + mi; if (mt >= MTILES) mt = 0;
    Ap[mi] = Xb + (size_t)mt * 8192 + lane * 8;
  }
  // wave stages tt = wid*4 .. wid*4+3 for both k-tiles of the phase
  const unsigned short* Wp = Wb + (size_t)(wid * 4) * 16 * 512 + lane * 8;

  for (int s = 0; s < 8; ++s) {
#pragma unroll
    for (int i = 0; i < 8; ++i) {
      int tti = i & 3, ktl = i >> 2;
      const unsigned short* gp = Wp + (size_t)(tti * 16 + s * 2 + ktl) * 512;
      gload_lds16(gp, sB + (ktl * 32 + wid * 4 + tti) * 512);
    }
    // A fragments for this phase (issued pre-barrier; drain shares the stage wait)
    short8 a[4][2];
#pragma unroll
    for (int mi = 0; mi < 4; ++mi)
#pragma unroll
      for (int kp = 0; kp < 2; ++kp)
        a[mi][kp] = *(const short8*)(Ap[mi] + (size_t)(s * 2 + kp) * 512);
    __syncthreads();
    // B fragments: 8 n-tiles x 2 k-tiles, constant offsets off one base
    short8 b[4][2][2];   // [g][nt][kp]
#pragma unroll
    for (int g = 0; g < 4; ++g)
#pragma unroll
      for (int nt = 0; nt < 2; ++nt) {
        int tt = g * 8 + cg * 2 + nt;
#pragma unroll
        for (int kp = 0; kp < 2; ++kp)
          b[g][nt][kp] = *(const short8*)(sB + (kp * 32 + tt) * 512 + lane * 8);
      }
#pragma unroll
    for (int mi = 0; mi < 4; ++mi)
#pragma unroll
      for (int g = 0; g < 4; ++g)
#pragma unroll
        for (int nt = 0; nt < 2; ++nt) {
          acc[mi][g][nt] = __builtin_amdgcn_mfma_f32_16x16x32_bf16(a[mi][0], b[g][nt][0], acc[mi][g][nt], 0, 0, 0);
          acc[mi][g][nt] = __builtin_amdgcn_mfma_f32_16x16x32_bf16(a[mi][1], b[g][nt][1], acc[mi][g][nt], 0, 0, 0);
        }
    __syncthreads();
  }

  // fused GRU epilogue: wave owns out cols [cg*32, cg*32+32), rows = its 4 mtiles
#pragma unroll
  for (int nt = 0; nt < 2; ++nt) {
    int cc = cg * 32 + nt * 16 + col16;
    float bbr = bb[cc], bbz = bb[128 + cc], bbn = bb[256 + cc], bbh = bb[384 + cc];
#pragma unroll
    for (int mi = 0; mi < 4; ++mi) {
      int mt = mbase + mi;
      if (mt >= MTILES) continue;
#pragma unroll
      for (int r = 0; r < 4; ++r) {
        int row = mt * 16 + quad * 4 + r;
        float rp  = acc[mi][0][nt][r] + bbr;
        float zp  = acc[mi][1][nt][r] + bbz;
        float inp = acc[mi][2][nt][r] + bbn;
        float hnp = acc[mi][3][nt][r] + bbh;
        float rg = 1.0f / (1.0f + __expf(-rp));
        float zg = 1.0f / (1.0f + __expf(-zp));
        float ng = tanhf(inp + rg * hnp);
        float hv = (row < NUSERS) ? sj_r[(size_t)row * 128 + cc]
                                  : sj[(size_t)(row - NUSERS) * 128 + cc];
        out[(size_t)row * 128 + cc] = (1.0f - zg) * ng + zg * hv;
      }
    }
  }
}

extern "C" void kernel_launch(void* const* d_in, const int* in_sizes, int n_in,
                              void* d_out, int out_size, void* d_ws, size_t ws_size,
                              hipStream_t stream) {
  const float* si   = (const float*)d_in[0];
  const float* sj   = (const float*)d_in[1];
  const float* si_r = (const float*)d_in[2];
  const float* sj_r = (const float*)d_in[3];
  const float* t    = (const float*)d_in[4];
  const float* t_r  = (const float*)d_in[5];
  const float* e    = (const float*)d_in[6];
  const float* e_r  = (const float*)d_in[7];
  const float* w_ih = (const float*)d_in[8];
  const float* w_hh = (const float*)d_in[9];
  const float* b_ih = (const float*)d_in[10];
  const float* b_hh = (const float*)d_in[11];
  const int* src_g  = (const int*)d_in[12];
  const int* dst_g  = (const int*)d_in[13];
  const int* src_gr = (const int*)d_in[14];
  const int* dst_gr = (const int*)d_in[15];
  int E = in_sizes[4];

  // workspace layout (16B-aligned head first)
  unsigned short* Xb = (unsigned short*)d_ws;          // 51,200,000 shorts (102.4 MB)
  unsigned short* Wb = Xb + (size_t)MTILES * 8192;     // 262144 shorts
  float* bb   = (float*)(Wb + 262144);                 // 512
  int* deg_j  = (int*)(bb + 512);                      // 50000  (memset target, with deg_i)
  int* deg_i  = deg_j + NNODE;                         // 50000
  int* rs_j   = deg_i + NNODE;                         // 50000
  int* rs_i   = rs_j + NNODE;                          // 50000
  int* cur_j  = rs_i + NNODE;                          // 50000
  int* cur_i  = cur_j + NNODE;                         // 50000
  int* csum   = cur_i + NNODE;                         // 2*NCHUNK
  int* coff   = csum + 2 * NCHUNK;                     // 2*NCHUNK (ends 16B-aligned)
  int4* recP_j = (int4*)(coff + 2 * NCHUNK);           // E int4
  int4* recP_i = recP_j + E;                           // E int4
  unsigned short* si_b  = (unsigned short*)(recP_i + E);  // 6.4M shorts (12.8 MB)
  unsigned short* sir_b = si_b + 6400000;                 // 6.4M shorts (12.8 MB)

  hipMemsetAsync(deg_j, 0, 2 * NNODE * sizeof(int), stream);

  pack_w_kernel<<<(512 * 512) / 256, 256, 0, stream>>>(w_ih, w_hh, b_ih, b_hh, Wb, bb);
  cast_mem_kernel<<<6250, 256, 0, stream>>>(si, si_r, si_b, sir_b);

  int blks2E = (2 * E + 255) / 256;
  hist_kernel<<<blks2E, 256, 0, stream>>>(dst_g, dst_gr, deg_j, deg_i, E);
  chunksum_kernel<<<2 * NCHUNK, 256, 0, stream>>>(deg_j, deg_i, csum);
  chunkscan_kernel<<<2, 256, 0, stream>>>(csum, coff);
  localscan_kernel<<<2 * NCHUNK, 256, 0, stream>>>(deg_j, deg_i, coff, rs_j, cur_j, rs_i, cur_i);
  fill_kernel<<<blks2E, 256, 0, stream>>>(src_g, dst_g, t, src_gr, dst_gr, t_r,
                                          cur_j, cur_i, recP_j, recP_i, E);

  gather_kernel<<<NTOT / 4, 256, 0, stream>>>(si_b, sir_b, sj, sj_r, e, e_r,
                                              rs_j, rs_i, deg_j, deg_i,
                                              recP_j, recP_i, Xb);

  float* out = (float*)d_out;
  gemm_gru_kernel<<<(MTILES + 7) / 8, 512, 0, stream>>>(Xb, Wb, bb, sj_r, sj, out);
}

// Round 5
// 622.276 us; speedup vs baseline: 2.0422x; 2.0422x over previous
//
#include <hip/hip_runtime.h>
#include <math.h>

#define NUSERS 50000
#define NITEMS 50000
#define NTOT   100000
#define NNODE  50000      // per direction
#define NCHUNK 196        // ceil(50000/256)
#define MTILES 6250       // 100000/16 row tiles
#define KDIM   512

typedef __attribute__((ext_vector_type(4))) float f32x4;
typedef __attribute__((ext_vector_type(8))) short short8;
typedef unsigned int u32;

#define AS1 __attribute__((address_space(1)))
#define AS3 __attribute__((address_space(3)))

static __device__ __forceinline__ unsigned short f2bf(float f) {
  unsigned int u = __float_as_uint(f);
  u += 0x7fffu + ((u >> 16) & 1u);
  return (unsigned short)(u >> 16);
}

static __device__ __forceinline__ u32 pack2(float x, float y) {
  return (u32)f2bf(x) | ((u32)f2bf(y) << 16);
}

static __device__ __forceinline__ void gload_lds16(const void* g, void* l) {
  __builtin_amdgcn_global_load_lds((const AS1 u32*)g, (AS3 u32*)l, 16, 0, 0);
}

// ---------------- pack W'' into MFMA B-fragment order -----------------
__global__ void pack_w_kernel(const float* __restrict__ w_ih,
                              const float* __restrict__ w_hh,
                              const float* __restrict__ b_ih,
                              const float* __restrict__ b_hh,
                              unsigned short* __restrict__ Wb,
                              float* __restrict__ bb) {
  int idx = blockIdx.x * 256 + threadIdx.x;       // 0 .. 512*512-1
  int j = idx & 7, l = (idx >> 3) & 63, ktt = idx >> 9;
  int kt = ktt & 15, tt = ktt >> 4;
  int g = tt * 16 + (l & 15);
  int k = kt * 32 + (l >> 4) * 8 + j;
  float v;
  if (g < 256)      v = (k < 384) ? w_ih[g * 384 + k] : w_hh[g * 128 + (k - 384)];
  else if (g < 384) v = (k < 384) ? w_ih[g * 384 + k] : 0.0f;
  else              v = (k < 384) ? 0.0f : w_hh[(g - 128) * 128 + (k - 384)];
  Wb[idx] = f2bf(v);
  if (idx < 512) {
    float b = (idx < 256) ? (b_ih[idx] + b_hh[idx])
            : (idx < 384) ? b_ih[idx]
                          : b_hh[idx - 128];
    bb[idx] = b;
  }
}

// ---------------- bf16 pre-cast of gathered memory rows -----------------
__global__ void cast_mem_kernel(const float* __restrict__ si,
                                const float* __restrict__ si_r,
                                unsigned short* __restrict__ si_b,
                                unsigned short* __restrict__ sir_b) {
  int i = blockIdx.x * 256 + threadIdx.x;          // 0 .. 1,599,999 (8 floats each)
  const float* src; unsigned short* dst; int off;
  if (i < 800000) { src = si;   dst = si_b;  off = i; }
  else            { src = si_r; dst = sir_b; off = i - 800000; }
  const f32x4* p = (const f32x4*)(src + (size_t)off * 8);
  f32x4 a = p[0], b = p[1];
  short8 o;
  o[0] = f2bf(a[0]); o[1] = f2bf(a[1]); o[2] = f2bf(a[2]); o[3] = f2bf(a[3]);
  o[4] = f2bf(b[0]); o[5] = f2bf(b[1]); o[6] = f2bf(b[2]); o[7] = f2bf(b[3]);
  *(short8*)(dst + (size_t)off * 8) = o;
}

// ---------------- CSR build -----------------
__global__ void hist_kernel(const int* __restrict__ dst_g,
                            const int* __restrict__ dst_gr,
                            int* __restrict__ deg_j, int* __restrict__ deg_i, int E) {
  int i = blockIdx.x * 256 + threadIdx.x;
  if (i < E) atomicAdd(&deg_j[dst_g[i]], 1);
  else if (i < 2 * E) atomicAdd(&deg_i[dst_gr[i - E]], 1);
}

__global__ void chunksum_kernel(const int* __restrict__ deg_j,
                                const int* __restrict__ deg_i,
                                int* __restrict__ csum) {
  int c = blockIdx.x;                    // 0..2*NCHUNK-1
  const int* deg = (c < NCHUNK) ? deg_j : deg_i;
  int cc = (c < NCHUNK) ? c : c - NCHUNK;
  int t = threadIdx.x;
  int idx = cc * 256 + t;
  int v = (idx < NNODE) ? deg[idx] : 0;
  for (int off = 32; off; off >>= 1) v += __shfl_down(v, off, 64);
  __shared__ int wsum[4];
  if ((t & 63) == 0) wsum[t >> 6] = v;
  __syncthreads();
  if (t == 0) csum[c] = wsum[0] + wsum[1] + wsum[2] + wsum[3];
}

__global__ void chunkscan_kernel(const int* __restrict__ csum, int* __restrict__ coff) {
  int d = blockIdx.x;                    // 0 or 1
  const int* cs = csum + d * NCHUNK;
  int* co = coff + d * NCHUNK;
  int t = threadIdx.x, lane = t & 63, w = t >> 6;
  int v = (t < NCHUNK) ? cs[t] : 0;
  int x = v;
  for (int off = 1; off < 64; off <<= 1) {
    int y = __shfl_up(x, off, 64);
    if (lane >= off) x += y;
  }
  __shared__ int wt[4];
  if (lane == 63) wt[w] = x;
  __syncthreads();
  int add = 0;
  for (int k = 0; k < 4; ++k) if (k < w) add += wt[k];
  if (t < NCHUNK) co[t] = add + x - v;   // exclusive prefix
}

__global__ void localscan_kernel(const int* __restrict__ deg_j,
                                 const int* __restrict__ deg_i,
                                 const int* __restrict__ coff,
                                 int* __restrict__ rs_j, int* __restrict__ cur_j,
                                 int* __restrict__ rs_i, int* __restrict__ cur_i) {
  int c = blockIdx.x;
  bool dj = c < NCHUNK;
  const int* deg = dj ? deg_j : deg_i;
  int cc = dj ? c : c - NCHUNK;
  int* rs = dj ? rs_j : rs_i;
  int* cur = dj ? cur_j : cur_i;
  int base = coff[c];
  int t = threadIdx.x, lane = t & 63, w = t >> 6;
  int idx = cc * 256 + t;
  int v = (idx < NNODE) ? deg[idx] : 0;
  int x = v;
  for (int off = 1; off < 64; off <<= 1) {
    int y = __shfl_up(x, off, 64);
    if (lane >= off) x += y;
  }
  __shared__ int wt[4];
  if (lane == 63) wt[w] = x;
  __syncthreads();
  int add = 0;
  for (int k = 0; k < 4; ++k) if (k < w) add += wt[k];
  int ex = base + add + x - v;
  if (idx < NNODE) { rs[idx] = ex; cur[idx] = ex; }
}

// fill: one 16B record per edge: (src, eid, ts_bits, 0)
__global__ void fill_kernel(const int* __restrict__ src_g, const int* __restrict__ dst_g,
                            const float* __restrict__ t,
                            const int* __restrict__ src_gr, const int* __restrict__ dst_gr,
                            const float* __restrict__ t_r,
                            int* __restrict__ cur_j, int* __restrict__ cur_i,
                            int4* __restrict__ recP_j, int4* __restrict__ recP_i,
                            int E) {
  int i = blockIdx.x * 256 + threadIdx.x;
  if (i < E) {
    int pos = atomicAdd(&cur_j[dst_g[i]], 1);
    recP_j[pos] = make_int4(src_g[i], i, __float_as_int(t[i]), 0);
  } else if (i < 2 * E) {
    int k = i - E;
    int pos = atomicAdd(&cur_i[dst_gr[k]], 1);
    recP_i[pos] = make_int4(src_gr[k], k, __float_as_int(t_r[k]), 0);
  }
}

// ---------------- gather: mean-message + pack X row in A-fragment order ----------------
// packed k layout: [0,128)=mean src_mem, [128,256)=h*(deg>0), [256,320)=mean tenc,
// [320,384)=mean edge feat, [384,512)=h
__global__ __launch_bounds__(256) void gather_kernel(
    const unsigned short* __restrict__ si_b, const unsigned short* __restrict__ sir_b,
    const float* __restrict__ sj, const float* __restrict__ sj_r,
    const float* __restrict__ e, const float* __restrict__ e_r,
    const int* __restrict__ rs_j, const int* __restrict__ rs_i,
    const int* __restrict__ deg_j, const int* __restrict__ deg_i,
    const int4* __restrict__ recP_j, const int4* __restrict__ recP_i,
    unsigned short* __restrict__ Xb) {
  __shared__ __align__(16) unsigned short rowbuf[4][512];
  int wid = threadIdx.x >> 6, lane = threadIdx.x & 63;
  int node = blockIdx.x * 4 + wid;                 // 0..99999
  bool user = node < NUSERS;
  int idx = user ? node : node - NUSERS;
  const unsigned short* smem = user ? sir_b : si_b;   // bf16 rows, 128 shorts
  const float* h    = user ? sj_r : sj;
  const float* ef   = user ? e_r : e;
  int start = __builtin_amdgcn_readfirstlane((user ? rs_i : rs_j)[idx]);
  int deg   = __builtin_amdgcn_readfirstlane((user ? deg_i : deg_j)[idx]);
  const int4* rec = user ? recP_i : recP_j;

  // freq[lane] = 10^(-9*lane/63) = exp(-lane * 9/63 * ln 10)
  float freq = __expf((float)lane * -0.3289407276f);
  // h row: issue early, consumed only in the epilogue
  float2 hvf = *(const float2*)(h + (size_t)idx * 128 + 2 * lane);

  float asx = 0.f, asy = 0.f;   // mean src_mem, k = 2*lane, 2*lane+1
  float at  = 0.f;              // tenc, k = 256+lane
  float ae  = 0.f;              // edge feat, k = 320+lane

  for (int base = 0; base < deg; base += 64) {
    int nn = deg - base; if (nn > 64) nn = 64;
    // cooperative record load: lane l holds record base+l (clamped)
    int cl = (lane < nn) ? base + lane : base + nn - 1;
    int4 r = rec[start + cl];
    for (int j0 = 0; j0 < nn; j0 += 8) {
      int j1 = (j0 + 1 < nn) ? j0 + 1 : nn - 1;
      int j2 = (j0 + 2 < nn) ? j0 + 2 : nn - 1;
      int j3 = (j0 + 3 < nn) ? j0 + 3 : nn - 1;
      int j4 = (j0 + 4 < nn) ? j0 + 4 : nn - 1;
      int j5 = (j0 + 5 < nn) ? j0 + 5 : nn - 1;
      int j6 = (j0 + 6 < nn) ? j0 + 6 : nn - 1;
      int j7 = (j0 + 7 < nn) ? j0 + 7 : nn - 1;
      float w1 = (j0 + 1 < nn) ? 1.0f : 0.0f;
      float w2 = (j0 + 2 < nn) ? 1.0f : 0.0f;
      float w3 = (j0 + 3 < nn) ? 1.0f : 0.0f;
      float w4 = (j0 + 4 < nn) ? 1.0f : 0.0f;
      float w5 = (j0 + 5 < nn) ? 1.0f : 0.0f;
      float w6 = (j0 + 6 < nn) ? 1.0f : 0.0f;
      float w7 = (j0 + 7 < nn) ? 1.0f : 0.0f;

      int s0 = __builtin_amdgcn_readlane(r.x, j0), e0 = __builtin_amdgcn_readlane(r.y, j0);
      int s1 = __builtin_amdgcn_readlane(r.x, j1), e1 = __builtin_amdgcn_readlane(r.y, j1);
      int s2 = __builtin_amdgcn_readlane(r.x, j2), e2 = __builtin_amdgcn_readlane(r.y, j2);
      int s3 = __builtin_amdgcn_readlane(r.x, j3), e3 = __builtin_amdgcn_readlane(r.y, j3);
      int s4 = __builtin_amdgcn_readlane(r.x, j4), e4 = __builtin_amdgcn_readlane(r.y, j4);
      int s5 = __builtin_amdgcn_readlane(r.x, j5), e5 = __builtin_amdgcn_readlane(r.y, j5);
      int s6 = __builtin_amdgcn_readlane(r.x, j6), e6 = __builtin_amdgcn_readlane(r.y, j6);
      int s7 = __builtin_amdgcn_readlane(r.x, j7), e7 = __builtin_amdgcn_readlane(r.y, j7);

      u32 v0 = *(const u32*)(smem + ((size_t)s0 << 7) + 2 * lane);
      u32 v1 = *(const u32*)(smem + ((size_t)s1 << 7) + 2 * lane);
      u32 v2 = *(const u32*)(smem + ((size_t)s2 << 7) + 2 * lane);
      u32 v3 = *(const u32*)(smem + ((size_t)s3 << 7) + 2 * lane);
      u32 v4 = *(const u32*)(smem + ((size_t)s4 << 7) + 2 * lane);
      u32 v5 = *(const u32*)(smem + ((size_t)s5 << 7) + 2 * lane);
      u32 v6 = *(const u32*)(smem + ((size_t)s6 << 7) + 2 * lane);
      u32 v7 = *(const u32*)(smem + ((size_t)s7 << 7) + 2 * lane);
      float f0 = ef[((size_t)e0 << 6) + lane];
      float f1 = ef[((size_t)e1 << 6) + lane];
      float f2 = ef[((size_t)e2 << 6) + lane];
      float f3 = ef[((size_t)e3 << 6) + lane];
      float f4 = ef[((size_t)e4 << 6) + lane];
      float f5 = ef[((size_t)e5 << 6) + lane];
      float f6 = ef[((size_t)e6 << 6) + lane];
      float f7 = ef[((size_t)e7 << 6) + lane];

      float c0 = __cosf(__int_as_float(__builtin_amdgcn_readlane(r.z, j0)) * freq);
      float c1 = __cosf(__int_as_float(__builtin_amdgcn_readlane(r.z, j1)) * freq);
      float c2 = __cosf(__int_as_float(__builtin_amdgcn_readlane(r.z, j2)) * freq);
      float c3 = __cosf(__int_as_float(__builtin_amdgcn_readlane(r.z, j3)) * freq);
      float c4 = __cosf(__int_as_float(__builtin_amdgcn_readlane(r.z, j4)) * freq);
      float c5 = __cosf(__int_as_float(__builtin_amdgcn_readlane(r.z, j5)) * freq);
      float c6 = __cosf(__int_as_float(__builtin_amdgcn_readlane(r.z, j6)) * freq);
      float c7 = __cosf(__int_as_float(__builtin_amdgcn_readlane(r.z, j7)) * freq);

      // unpack bf16 pair and accumulate (weighted for clamped tail slots)
      float l0 = __uint_as_float(v0 << 16), g0 = __uint_as_float(v0 & 0xffff0000u);
      float l1 = __uint_as_float(v1 << 16), g1 = __uint_as_float(v1 & 0xffff0000u);
      float l2 = __uint_as_float(v2 << 16), g2 = __uint_as_float(v2 & 0xffff0000u);
      float l3 = __uint_as_float(v3 << 16), g3 = __uint_as_float(v3 & 0xffff0000u);
      float l4 = __uint_as_float(v4 << 16), g4 = __uint_as_float(v4 & 0xffff0000u);
      float l5 = __uint_as_float(v5 << 16), g5 = __uint_as_float(v5 & 0xffff0000u);
      float l6 = __uint_as_float(v6 << 16), g6 = __uint_as_float(v6 & 0xffff0000u);
      float l7 = __uint_as_float(v7 << 16), g7 = __uint_as_float(v7 & 0xffff0000u);

      asx += l0 + w1 * l1 + w2 * l2 + w3 * l3 + w4 * l4 + w5 * l5 + w6 * l6 + w7 * l7;
      asy += g0 + w1 * g1 + w2 * g2 + w3 * g3 + w4 * g4 + w5 * g5 + w6 * g6 + w7 * g7;
      at  += c0 + w1 * c1 + w2 * c2 + w3 * c3 + w4 * c4 + w5 * c5 + w6 * c6 + w7 * c7;
      ae  += f0 + w1 * f1 + w2 * f2 + w3 * f3 + w4 * f4 + w5 * f5 + w6 * f6 + w7 * f7;
    }
  }

  float invc = (deg > 0) ? 1.0f / (float)deg : 0.0f;
  float hz   = (deg > 0) ? 1.0f : 0.0f;

  unsigned short* rb = rowbuf[wid];
  u32* rb32 = (u32*)rb;
  rb32[lane]       = pack2(asx * invc, asy * invc);   // k = 2*lane,2*lane+1
  rb32[64 + lane]  = pack2(hvf.x * hz, hvf.y * hz);   // k = 128+2*lane
  rb[256 + lane]   = f2bf(at * invc);                 // k = 256+lane
  rb[320 + lane]   = f2bf(ae * invc);                 // k = 320+lane
  rb32[192 + lane] = pack2(hvf.x, hvf.y);             // k = 384+2*lane

  // wave-private LDS: compiler orders ds_write -> ds_read via lgkmcnt, no barrier
  // transpose-write in A-fragment order: lane owns k = lane*8 .. lane*8+8
  int rt = node >> 4, m = node & 15;
  int kt2 = lane >> 2, q2 = lane & 3;
  short8 vv = *(const short8*)(rb + lane * 8);
  *(short8*)(Xb + (((size_t)rt * 16 + kt2) * 64 + q2 * 16 + m) * 8) = vv;
}

// ---------------- GEMM (100000 x 512) @ W''^T with fused GRU epilogue ----------------
// v5: high-occupancy, all-LDS inner loop.
// Block = 1024 thr (16 waves = 2 mg x 8 cg), tile 4 mtiles x 512 cols, grid 1563.
// sA (64KB): 4 mtiles x full K staged ONCE via global_load_lds (only HBM in kernel).
// sW (2x32KB dbuf): K=32 slice; stage kt+1 issued before compute of kt (drain
// overlaps compute; single barrier per step).
// Wave = 2 mtiles x 64 gemm-cols (16 per gate): acc[2][4] = 32 regs, a 8, b 16
// -> ~90 regs total -> 4 waves/SIMD. Inner step: 6 ds_read_b128 + 8 MFMA.
__global__ __launch_bounds__(1024, 4) void gemm_gru_kernel(
    const unsigned short* __restrict__ Xb,
    const unsigned short* __restrict__ Wb,
    const float* __restrict__ bb,
    const float* __restrict__ sj_r,
    const float* __restrict__ sj,
    float* __restrict__ out) {
  __shared__ __align__(16) unsigned short sA[32768];      // 64 KB: [mt][kt][512]
  __shared__ __align__(16) unsigned short sW[2][16384];   // 2 x 32 KB: [tt][512]
  int wid = threadIdx.x >> 6, lane = threadIdx.x & 63;
  int mg = wid >> 3, cg = wid & 7;
  int mbase = blockIdx.x * 4;
  int col16 = lane & 15, quad = lane >> 4;

  f32x4 acc[2][4];
#pragma unroll
  for (int mi = 0; mi < 2; ++mi)
#pragma unroll
    for (int g = 0; g < 4; ++g) acc[mi][g] = (f32x4)0.0f;

  // ---- prologue staging ----
  // sA: 64 slices (mt 0..3 x kt 0..15), 4 per wave
#pragma unroll
  for (int i = 0; i < 4; ++i) {
    int u = wid * 4 + i;                       // 0..63
    int mt = mbase + (u >> 4);
    if (mt >= MTILES) mt = MTILES - 1;
    const unsigned short* gp = Xb + (size_t)mt * 8192 + (u & 15) * 512 + lane * 8;
    gload_lds16(gp, sA + u * 512);
  }
  // sW[0]: kt=0 slice, 32 slices (tt 0..31), 2 per wave
#pragma unroll
  for (int i = 0; i < 2; ++i) {
    int tt = wid * 2 + i;                      // 0..31
    const unsigned short* gp = Wb + ((size_t)(tt * 16 + 0) * 64 + lane) * 8;
    gload_lds16(gp, sW[0] + tt * 512);
  }
  __syncthreads();

  const unsigned short* aBase = sA + (size_t)(mg * 32) * 512 + lane * 8;

  for (int kt = 0; kt < 16; ++kt) {
    int cur = kt & 1;
    if (kt < 15) {
#pragma unroll
      for (int i = 0; i < 2; ++i) {
        int tt = wid * 2 + i;
        const unsigned short* gp = Wb + ((size_t)(tt * 16 + kt + 1) * 64 + lane) * 8;
        gload_lds16(gp, sW[cur ^ 1] + tt * 512);
      }
    }
    short8 a0 = *(const short8*)(aBase + (size_t)kt * 512);
    short8 a1 = *(const short8*)(aBase + (size_t)(16 + kt) * 512);
    short8 b0 = *(const short8*)(sW[cur] + (0 * 8 + cg) * 512 + lane * 8);
    short8 b1 = *(const short8*)(sW[cur] + (1 * 8 + cg) * 512 + lane * 8);
    short8 b2 = *(const short8*)(sW[cur] + (2 * 8 + cg) * 512 + lane * 8);
    short8 b3 = *(const short8*)(sW[cur] + (3 * 8 + cg) * 512 + lane * 8);
    acc[0][0] = __builtin_amdgcn_mfma_f32_16x16x32_bf16(a0, b0, acc[0][0], 0, 0, 0);
    acc[0][1] = __builtin_amdgcn_mfma_f32_16x16x32_bf16(a0, b1, acc[0][1], 0, 0, 0);
    acc[0][2] = __builtin_amdgcn_mfma_f32_16x16x32_bf16(a0, b2, acc[0][2], 0, 0, 0);
    acc[0][3] = __builtin_amdgcn_mfma_f32_16x16x32_bf16(a0, b3, acc[0][3], 0, 0, 0);
    acc[1][0] = __builtin_amdgcn_mfma_f32_16x16x32_bf16(a1, b0, acc[1][0], 0, 0, 0);
    acc[1][1] = __builtin_amdgcn_mfma_f32_16x16x32_bf16(a1, b1, acc[1][1], 0, 0, 0);
    acc[1][2] = __builtin_amdgcn_mfma_f32_16x16x32_bf16(a1, b2, acc[1][2], 0, 0, 0);
    acc[1][3] = __builtin_amdgcn_mfma_f32_16x16x32_bf16(a1, b3, acc[1][3], 0, 0, 0);
    __syncthreads();
  }

  // fused GRU epilogue: wave owns out cols [cg*16, cg*16+16), rows = its 2 mtiles
  int cc = cg * 16 + col16;
  float bbr = bb[cc], bbz = bb[128 + cc], bbn = bb[256 + cc], bbh = bb[384 + cc];
#pragma unroll
  for (int mi = 0; mi < 2; ++mi) {
    int mt = mbase + mg * 2 + mi;
    if (mt >= MTILES) continue;
#pragma unroll
    for (int r = 0; r < 4; ++r) {
      int row = mt * 16 + quad * 4 + r;
      float rp  = acc[mi][0][r] + bbr;
      float zp  = acc[mi][1][r] + bbz;
      float inp = acc[mi][2][r] + bbn;
      float hnp = acc[mi][3][r] + bbh;
      float rg = 1.0f / (1.0f + __expf(-rp));
      float zg = 1.0f / (1.0f + __expf(-zp));
      float ng = tanhf(inp + rg * hnp);
      float hv = (row < NUSERS) ? sj_r[(size_t)row * 128 + cc]
                                : sj[(size_t)(row - NUSERS) * 128 + cc];
      out[(size_t)row * 128 + cc] = (1.0f - zg) * ng + zg * hv;
    }
  }
}

extern "C" void kernel_launch(void* const* d_in, const int* in_sizes, int n_in,
                              void* d_out, int out_size, void* d_ws, size_t ws_size,
                              hipStream_t stream) {
  const float* si   = (const float*)d_in[0];
  const float* sj   = (const float*)d_in[1];
  const float* si_r = (const float*)d_in[2];
  const float* sj_r = (const float*)d_in[3];
  const float* t    = (const float*)d_in[4];
  const float* t_r  = (const float*)d_in[5];
  const float* e    = (const float*)d_in[6];
  const float* e_r  = (const float*)d_in[7];
  const float* w_ih = (const float*)d_in[8];
  const float* w_hh = (const float*)d_in[9];
  const float* b_ih = (const float*)d_in[10];
  const float* b_hh = (const float*)d_in[11];
  const int* src_g  = (const int*)d_in[12];
  const int* dst_g  = (const int*)d_in[13];
  const int* src_gr = (const int*)d_in[14];
  const int* dst_gr = (const int*)d_in[15];
  int E = in_sizes[4];

  // workspace layout (16B-aligned head first)
  unsigned short* Xb = (unsigned short*)d_ws;          // 51,200,000 shorts (102.4 MB)
  unsigned short* Wb = Xb + (size_t)MTILES * 8192;     // 262144 shorts
  float* bb   = (float*)(Wb + 262144);                 // 512
  int* deg_j  = (int*)(bb + 512);                      // 50000  (memset target, with deg_i)
  int* deg_i  = deg_j + NNODE;                         // 50000
  int* rs_j   = deg_i + NNODE;                         // 50000
  int* rs_i   = rs_j + NNODE;                          // 50000
  int* cur_j  = rs_i + NNODE;                          // 50000
  int* cur_i  = cur_j + NNODE;                         // 50000
  int* csum   = cur_i + NNODE;                         // 2*NCHUNK
  int* coff   = csum + 2 * NCHUNK;                     // 2*NCHUNK (ends 16B-aligned)
  int4* recP_j = (int4*)(coff + 2 * NCHUNK);           // E int4
  int4* recP_i = recP_j + E;                           // E int4
  unsigned short* si_b  = (unsigned short*)(recP_i + E);  // 6.4M shorts (12.8 MB)
  unsigned short* sir_b = si_b + 6400000;                 // 6.4M shorts (12.8 MB)

  hipMemsetAsync(deg_j, 0, 2 * NNODE * sizeof(int), stream);

  pack_w_kernel<<<(512 * 512) / 256, 256, 0, stream>>>(w_ih, w_hh, b_ih, b_hh, Wb, bb);
  cast_mem_kernel<<<6250, 256, 0, stream>>>(si, si_r, si_b, sir_b);

  int blks2E = (2 * E + 255) / 256;
  hist_kernel<<<blks2E, 256, 0, stream>>>(dst_g, dst_gr, deg_j, deg_i, E);
  chunksum_kernel<<<2 * NCHUNK, 256, 0, stream>>>(deg_j, deg_i, csum);
  chunkscan_kernel<<<2, 256, 0, stream>>>(csum, coff);
  localscan_kernel<<<2 * NCHUNK, 256, 0, stream>>>(deg_j, deg_i, coff, rs_j, cur_j, rs_i, cur_i);
  fill_kernel<<<blks2E, 256, 0, stream>>>(src_g, dst_g, t, src_gr, dst_gr, t_r,
                                          cur_j, cur_i, recP_j, recP_i, E);

  gather_kernel<<<NTOT / 4, 256, 0, stream>>>(si_b, sir_b, sj, sj_r, e, e_r,
                                              rs_j, rs_i, deg_j, deg_i,
                                              recP_j, recP_i, Xb);

  float* out = (float*)d_out;
  gemm_gru_kernel<<<(MTILES + 3) / 4, 1024, 0, stream>>>(Xb, Wb, bb, sj_r, sj, out);
}

// Round 6
// 592.518 us; speedup vs baseline: 2.1448x; 1.0502x over previous
//
#include <hip/hip_runtime.h>
#include <math.h>

#define NUSERS 50000
#define NITEMS 50000
#define NTOT   100000
#define NNODE  50000      // per direction
#define NCHUNK 196        // ceil(50000/256)
#define MTILES 6250       // 100000/16 row tiles
#define KDIM   512
#define NWAVES 8192       // gather: 2048 blocks x 4 waves, grid-stride over nodes

typedef __attribute__((ext_vector_type(4))) float f32x4;
typedef __attribute__((ext_vector_type(8))) short short8;
typedef unsigned int u32;

#define AS1 __attribute__((address_space(1)))
#define AS3 __attribute__((address_space(3)))

static __device__ __forceinline__ unsigned short f2bf(float f) {
  unsigned int u = __float_as_uint(f);
  u += 0x7fffu + ((u >> 16) & 1u);
  return (unsigned short)(u >> 16);
}

static __device__ __forceinline__ u32 pack2(float x, float y) {
  return (u32)f2bf(x) | ((u32)f2bf(y) << 16);
}

static __device__ __forceinline__ void gload_lds16(const void* g, void* l) {
  __builtin_amdgcn_global_load_lds((const AS1 u32*)g, (AS3 u32*)l, 16, 0, 0);
}

// ---------------- pack W'' into MFMA B-fragment order -----------------
__global__ void pack_w_kernel(const float* __restrict__ w_ih,
                              const float* __restrict__ w_hh,
                              const float* __restrict__ b_ih,
                              const float* __restrict__ b_hh,
                              unsigned short* __restrict__ Wb,
                              float* __restrict__ bb) {
  int idx = blockIdx.x * 256 + threadIdx.x;       // 0 .. 512*512-1
  int j = idx & 7, l = (idx >> 3) & 63, ktt = idx >> 9;
  int kt = ktt & 15, tt = ktt >> 4;
  int g = tt * 16 + (l & 15);
  int k = kt * 32 + (l >> 4) * 8 + j;
  float v;
  if (g < 256)      v = (k < 384) ? w_ih[g * 384 + k] : w_hh[g * 128 + (k - 384)];
  else if (g < 384) v = (k < 384) ? w_ih[g * 384 + k] : 0.0f;
  else              v = (k < 384) ? 0.0f : w_hh[(g - 128) * 128 + (k - 384)];
  Wb[idx] = f2bf(v);
  if (idx < 512) {
    float b = (idx < 256) ? (b_ih[idx] + b_hh[idx])
            : (idx < 384) ? b_ih[idx]
                          : b_hh[idx - 128];
    bb[idx] = b;
  }
}

// ---------------- bf16 pre-cast of gathered memory rows -----------------
__global__ void cast_mem_kernel(const float* __restrict__ si,
                                const float* __restrict__ si_r,
                                unsigned short* __restrict__ si_b,
                                unsigned short* __restrict__ sir_b) {
  int i = blockIdx.x * 256 + threadIdx.x;          // 0 .. 1,599,999 (8 floats each)
  const float* src; unsigned short* dst; int off;
  if (i < 800000) { src = si;   dst = si_b;  off = i; }
  else            { src = si_r; dst = sir_b; off = i - 800000; }
  const f32x4* p = (const f32x4*)(src + (size_t)off * 8);
  f32x4 a = p[0], b = p[1];
  short8 o;
  o[0] = f2bf(a[0]); o[1] = f2bf(a[1]); o[2] = f2bf(a[2]); o[3] = f2bf(a[3]);
  o[4] = f2bf(b[0]); o[5] = f2bf(b[1]); o[6] = f2bf(b[2]); o[7] = f2bf(b[3]);
  *(short8*)(dst + (size_t)off * 8) = o;
}

// ---------------- CSR build -----------------
__global__ void hist_kernel(const int* __restrict__ dst_g,
                            const int* __restrict__ dst_gr,
                            int* __restrict__ deg_j, int* __restrict__ deg_i, int E) {
  int i = blockIdx.x * 256 + threadIdx.x;
  if (i < E) atomicAdd(&deg_j[dst_g[i]], 1);
  else if (i < 2 * E) atomicAdd(&deg_i[dst_gr[i - E]], 1);
}

__global__ void chunksum_kernel(const int* __restrict__ deg_j,
                                const int* __restrict__ deg_i,
                                int* __restrict__ csum) {
  int c = blockIdx.x;                    // 0..2*NCHUNK-1
  const int* deg = (c < NCHUNK) ? deg_j : deg_i;
  int cc = (c < NCHUNK) ? c : c - NCHUNK;
  int t = threadIdx.x;
  int idx = cc * 256 + t;
  int v = (idx < NNODE) ? deg[idx] : 0;
  for (int off = 32; off; off >>= 1) v += __shfl_down(v, off, 64);
  __shared__ int wsum[4];
  if ((t & 63) == 0) wsum[t >> 6] = v;
  __syncthreads();
  if (t == 0) csum[c] = wsum[0] + wsum[1] + wsum[2] + wsum[3];
}

__global__ void chunkscan_kernel(const int* __restrict__ csum, int* __restrict__ coff) {
  int d = blockIdx.x;                    // 0 or 1
  const int* cs = csum + d * NCHUNK;
  int* co = coff + d * NCHUNK;
  int t = threadIdx.x, lane = t & 63, w = t >> 6;
  int v = (t < NCHUNK) ? cs[t] : 0;
  int x = v;
  for (int off = 1; off < 64; off <<= 1) {
    int y = __shfl_up(x, off, 64);
    if (lane >= off) x += y;
  }
  __shared__ int wt[4];
  if (lane == 63) wt[w] = x;
  __syncthreads();
  int add = 0;
  for (int k = 0; k < 4; ++k) if (k < w) add += wt[k];
  if (t < NCHUNK) co[t] = add + x - v;   // exclusive prefix
}

__global__ void localscan_kernel(const int* __restrict__ deg_j,
                                 const int* __restrict__ deg_i,
                                 const int* __restrict__ coff,
                                 int* __restrict__ rs_j, int* __restrict__ cur_j,
                                 int* __restrict__ rs_i, int* __restrict__ cur_i) {
  int c = blockIdx.x;
  bool dj = c < NCHUNK;
  const int* deg = dj ? deg_j : deg_i;
  int cc = dj ? c : c - NCHUNK;
  int* rs = dj ? rs_j : rs_i;
  int* cur = dj ? cur_j : cur_i;
  int base = coff[c];
  int t = threadIdx.x, lane = t & 63, w = t >> 6;
  int idx = cc * 256 + t;
  int v = (idx < NNODE) ? deg[idx] : 0;
  int x = v;
  for (int off = 1; off < 64; off <<= 1) {
    int y = __shfl_up(x, off, 64);
    if (lane >= off) x += y;
  }
  __shared__ int wt[4];
  if (lane == 63) wt[w] = x;
  __syncthreads();
  int add = 0;
  for (int k = 0; k < 4; ++k) if (k < w) add += wt[k];
  int ex = base + add + x - v;
  if (idx < NNODE) { rs[idx] = ex; cur[idx] = ex; }
}

// fill: one 16B record per edge: (src, eid, ts_bits, 0)
__global__ void fill_kernel(const int* __restrict__ src_g, const int* __restrict__ dst_g,
                            const float* __restrict__ t,
                            const int* __restrict__ src_gr, const int* __restrict__ dst_gr,
                            const float* __restrict__ t_r,
                            int* __restrict__ cur_j, int* __restrict__ cur_i,
                            int4* __restrict__ recP_j, int4* __restrict__ recP_i,
                            int E) {
  int i = blockIdx.x * 256 + threadIdx.x;
  if (i < E) {
    int pos = atomicAdd(&cur_j[dst_g[i]], 1);
    recP_j[pos] = make_int4(src_g[i], i, __float_as_int(t[i]), 0);
  } else if (i < 2 * E) {
    int k = i - E;
    int pos = atomicAdd(&cur_i[dst_gr[k]], 1);
    recP_i[pos] = make_int4(src_gr[k], k, __float_as_int(t_r[k]), 0);
  }
}

// ---------------- gather: mean-message, write X row NODE-MAJOR ----------------
// packed k layout: [0,128)=mean src_mem, [128,256)=h*(deg>0), [256,320)=mean tenc,
// [320,384)=mean edge feat, [384,512)=h
// Grid-stride node loop (8192 waves x ~12 nodes) -> degree imbalance averages out
// (was: 1 node/wave, block lifetime = max-of-4 degrees -> 64% occupancy).
// Inner loop split: unclamped full-8 rounds (no weights/clamps/dup loads) + one
// clamped tail. Xb write is node-major (1KB contiguous per node) -- the GEMM's
// sA staging does the fragment reordering via per-lane global src addresses.
__global__ __launch_bounds__(256) void gather_kernel(
    const unsigned short* __restrict__ si_b, const unsigned short* __restrict__ sir_b,
    const float* __restrict__ sj, const float* __restrict__ sj_r,
    const float* __restrict__ e, const float* __restrict__ e_r,
    const int* __restrict__ rs_j, const int* __restrict__ rs_i,
    const int* __restrict__ deg_j, const int* __restrict__ deg_i,
    const int4* __restrict__ recP_j, const int4* __restrict__ recP_i,
    unsigned short* __restrict__ Xb) {
  __shared__ __align__(16) unsigned short rowbuf[4][512];
  int wid = threadIdx.x >> 6, lane = threadIdx.x & 63;
  int gwave = blockIdx.x * 4 + wid;                // 0..NWAVES-1
  // freq[lane] = 10^(-9*lane/63) = exp(-lane * 9/63 * ln 10)
  float freq = __expf((float)lane * -0.3289407276f);
  unsigned short* rb = rowbuf[wid];
  u32* rb32 = (u32*)rb;

  for (int node = gwave; node < NTOT; node += NWAVES) {
    bool user = node < NUSERS;
    int idx = user ? node : node - NUSERS;
    const unsigned short* smem = user ? sir_b : si_b;   // bf16 rows, 128 shorts
    const float* h  = user ? sj_r : sj;
    const float* ef = user ? e_r : e;
    int start = __builtin_amdgcn_readfirstlane((user ? rs_i : rs_j)[idx]);
    int deg   = __builtin_amdgcn_readfirstlane((user ? deg_i : deg_j)[idx]);
    const int4* rec = user ? recP_i : recP_j;

    // h row: issue early, consumed only in the epilogue
    float2 hvf = *(const float2*)(h + (size_t)idx * 128 + 2 * lane);

    float asx = 0.f, asy = 0.f;   // mean src_mem, k = 2*lane, 2*lane+1
    float at  = 0.f;              // tenc, k = 256+lane
    float ae  = 0.f;              // edge feat, k = 320+lane

    for (int base = 0; base < deg; base += 64) {
      int nn = deg - base; if (nn > 64) nn = 64;
      // cooperative record load: lane l holds record base+l (clamped)
      int cl = (lane < nn) ? base + lane : base + nn - 1;
      int4 r = rec[start + cl];
      int full = nn & ~7;
      // ---- unclamped full rounds: no weights, no dup loads ----
      for (int j0 = 0; j0 < full; j0 += 8) {
        int s0 = __builtin_amdgcn_readlane(r.x, j0 + 0), e0 = __builtin_amdgcn_readlane(r.y, j0 + 0);
        int s1 = __builtin_amdgcn_readlane(r.x, j0 + 1), e1 = __builtin_amdgcn_readlane(r.y, j0 + 1);
        int s2 = __builtin_amdgcn_readlane(r.x, j0 + 2), e2 = __builtin_amdgcn_readlane(r.y, j0 + 2);
        int s3 = __builtin_amdgcn_readlane(r.x, j0 + 3), e3 = __builtin_amdgcn_readlane(r.y, j0 + 3);
        int s4 = __builtin_amdgcn_readlane(r.x, j0 + 4), e4 = __builtin_amdgcn_readlane(r.y, j0 + 4);
        int s5 = __builtin_amdgcn_readlane(r.x, j0 + 5), e5 = __builtin_amdgcn_readlane(r.y, j0 + 5);
        int s6 = __builtin_amdgcn_readlane(r.x, j0 + 6), e6 = __builtin_amdgcn_readlane(r.y, j0 + 6);
        int s7 = __builtin_amdgcn_readlane(r.x, j0 + 7), e7 = __builtin_amdgcn_readlane(r.y, j0 + 7);

        u32 v0 = *(const u32*)(smem + ((size_t)s0 << 7) + 2 * lane);
        u32 v1 = *(const u32*)(smem + ((size_t)s1 << 7) + 2 * lane);
        u32 v2 = *(const u32*)(smem + ((size_t)s2 << 7) + 2 * lane);
        u32 v3 = *(const u32*)(smem + ((size_t)s3 << 7) + 2 * lane);
        u32 v4 = *(const u32*)(smem + ((size_t)s4 << 7) + 2 * lane);
        u32 v5 = *(const u32*)(smem + ((size_t)s5 << 7) + 2 * lane);
        u32 v6 = *(const u32*)(smem + ((size_t)s6 << 7) + 2 * lane);
        u32 v7 = *(const u32*)(smem + ((size_t)s7 << 7) + 2 * lane);
        float f0 = ef[((size_t)e0 << 6) + lane];
        float f1 = ef[((size_t)e1 << 6) + lane];
        float f2 = ef[((size_t)e2 << 6) + lane];
        float f3 = ef[((size_t)e3 << 6) + lane];
        float f4 = ef[((size_t)e4 << 6) + lane];
        float f5 = ef[((size_t)e5 << 6) + lane];
        float f6 = ef[((size_t)e6 << 6) + lane];
        float f7 = ef[((size_t)e7 << 6) + lane];

        float c0 = __cosf(__int_as_float(__builtin_amdgcn_readlane(r.z, j0 + 0)) * freq);
        float c1 = __cosf(__int_as_float(__builtin_amdgcn_readlane(r.z, j0 + 1)) * freq);
        float c2 = __cosf(__int_as_float(__builtin_amdgcn_readlane(r.z, j0 + 2)) * freq);
        float c3 = __cosf(__int_as_float(__builtin_amdgcn_readlane(r.z, j0 + 3)) * freq);
        float c4 = __cosf(__int_as_float(__builtin_amdgcn_readlane(r.z, j0 + 4)) * freq);
        float c5 = __cosf(__int_as_float(__builtin_amdgcn_readlane(r.z, j0 + 5)) * freq);
        float c6 = __cosf(__int_as_float(__builtin_amdgcn_readlane(r.z, j0 + 6)) * freq);
        float c7 = __cosf(__int_as_float(__builtin_amdgcn_readlane(r.z, j0 + 7)) * freq);

        float l0 = __uint_as_float(v0 << 16), g0 = __uint_as_float(v0 & 0xffff0000u);
        float l1 = __uint_as_float(v1 << 16), g1 = __uint_as_float(v1 & 0xffff0000u);
        float l2 = __uint_as_float(v2 << 16), g2 = __uint_as_float(v2 & 0xffff0000u);
        float l3 = __uint_as_float(v3 << 16), g3 = __uint_as_float(v3 & 0xffff0000u);
        float l4 = __uint_as_float(v4 << 16), g4 = __uint_as_float(v4 & 0xffff0000u);
        float l5 = __uint_as_float(v5 << 16), g5 = __uint_as_float(v5 & 0xffff0000u);
        float l6 = __uint_as_float(v6 << 16), g6 = __uint_as_float(v6 & 0xffff0000u);
        float l7 = __uint_as_float(v7 << 16), g7 = __uint_as_float(v7 & 0xffff0000u);

        asx += ((l0 + l1) + (l2 + l3)) + ((l4 + l5) + (l6 + l7));
        asy += ((g0 + g1) + (g2 + g3)) + ((g4 + g5) + (g6 + g7));
        at  += ((c0 + c1) + (c2 + c3)) + ((c4 + c5) + (c6 + c7));
        ae  += ((f0 + f1) + (f2 + f3)) + ((f4 + f5) + (f6 + f7));
      }
      // ---- clamped tail (1..7 real edges) ----
      if (full < nn) {
        int j0 = full;
        int j1 = (j0 + 1 < nn) ? j0 + 1 : nn - 1;
        int j2 = (j0 + 2 < nn) ? j0 + 2 : nn - 1;
        int j3 = (j0 + 3 < nn) ? j0 + 3 : nn - 1;
        int j4 = (j0 + 4 < nn) ? j0 + 4 : nn - 1;
        int j5 = (j0 + 5 < nn) ? j0 + 5 : nn - 1;
        int j6 = (j0 + 6 < nn) ? j0 + 6 : nn - 1;
        float w1 = (j0 + 1 < nn) ? 1.0f : 0.0f;
        float w2 = (j0 + 2 < nn) ? 1.0f : 0.0f;
        float w3 = (j0 + 3 < nn) ? 1.0f : 0.0f;
        float w4 = (j0 + 4 < nn) ? 1.0f : 0.0f;
        float w5 = (j0 + 5 < nn) ? 1.0f : 0.0f;
        float w6 = (j0 + 6 < nn) ? 1.0f : 0.0f;

        int s0 = __builtin_amdgcn_readlane(r.x, j0), e0 = __builtin_amdgcn_readlane(r.y, j0);
        int s1 = __builtin_amdgcn_readlane(r.x, j1), e1 = __builtin_amdgcn_readlane(r.y, j1);
        int s2 = __builtin_amdgcn_readlane(r.x, j2), e2 = __builtin_amdgcn_readlane(r.y, j2);
        int s3 = __builtin_amdgcn_readlane(r.x, j3), e3 = __builtin_amdgcn_readlane(r.y, j3);
        int s4 = __builtin_amdgcn_readlane(r.x, j4), e4 = __builtin_amdgcn_readlane(r.y, j4);
        int s5 = __builtin_amdgcn_readlane(r.x, j5), e5 = __builtin_amdgcn_readlane(r.y, j5);
        int s6 = __builtin_amdgcn_readlane(r.x, j6), e6 = __builtin_amdgcn_readlane(r.y, j6);

        u32 v0 = *(const u32*)(smem + ((size_t)s0 << 7) + 2 * lane);
        u32 v1 = *(const u32*)(smem + ((size_t)s1 << 7) + 2 * lane);
        u32 v2 = *(const u32*)(smem + ((size_t)s2 << 7) + 2 * lane);
        u32 v3 = *(const u32*)(smem + ((size_t)s3 << 7) + 2 * lane);
        u32 v4 = *(const u32*)(smem + ((size_t)s4 << 7) + 2 * lane);
        u32 v5 = *(const u32*)(smem + ((size_t)s5 << 7) + 2 * lane);
        u32 v6 = *(const u32*)(smem + ((size_t)s6 << 7) + 2 * lane);
        float f0 = ef[((size_t)e0 << 6) + lane];
        float f1 = ef[((size_t)e1 << 6) + lane];
        float f2 = ef[((size_t)e2 << 6) + lane];
        float f3 = ef[((size_t)e3 << 6) + lane];
        float f4 = ef[((size_t)e4 << 6) + lane];
        float f5 = ef[((size_t)e5 << 6) + lane];
        float f6 = ef[((size_t)e6 << 6) + lane];

        float c0 = __cosf(__int_as_float(__builtin_amdgcn_readlane(r.z, j0)) * freq);
        float c1 = __cosf(__int_as_float(__builtin_amdgcn_readlane(r.z, j1)) * freq);
        float c2 = __cosf(__int_as_float(__builtin_amdgcn_readlane(r.z, j2)) * freq);
        float c3 = __cosf(__int_as_float(__builtin_amdgcn_readlane(r.z, j3)) * freq);
        float c4 = __cosf(__int_as_float(__builtin_amdgcn_readlane(r.z, j4)) * freq);
        float c5 = __cosf(__int_as_float(__builtin_amdgcn_readlane(r.z, j5)) * freq);
        float c6 = __cosf(__int_as_float(__builtin_amdgcn_readlane(r.z, j6)) * freq);

        float l0 = __uint_as_float(v0 << 16), g0 = __uint_as_float(v0 & 0xffff0000u);
        float l1 = __uint_as_float(v1 << 16), g1 = __uint_as_float(v1 & 0xffff0000u);
        float l2 = __uint_as_float(v2 << 16), g2 = __uint_as_float(v2 & 0xffff0000u);
        float l3 = __uint_as_float(v3 << 16), g3 = __uint_as_float(v3 & 0xffff0000u);
        float l4 = __uint_as_float(v4 << 16), g4 = __uint_as_float(v4 & 0xffff0000u);
        float l5 = __uint_as_float(v5 << 16), g5 = __uint_as_float(v5 & 0xffff0000u);
        float l6 = __uint_as_float(v6 << 16), g6 = __uint_as_float(v6 & 0xffff0000u);

        asx += l0 + w1 * l1 + w2 * l2 + w3 * l3 + w4 * l4 + w5 * l5 + w6 * l6;
        asy += g0 + w1 * g1 + w2 * g2 + w3 * g3 + w4 * g4 + w5 * g5 + w6 * g6;
        at  += c0 + w1 * c1 + w2 * c2 + w3 * c3 + w4 * c4 + w5 * c5 + w6 * c6;
        ae  += f0 + w1 * f1 + w2 * f2 + w3 * f3 + w4 * f4 + w5 * f5 + w6 * f6;
      }
    }

    float invc = (deg > 0) ? 1.0f / (float)deg : 0.0f;
    float hz   = (deg > 0) ? 1.0f : 0.0f;

    rb32[lane]       = pack2(asx * invc, asy * invc);   // k = 2*lane,2*lane+1
    rb32[64 + lane]  = pack2(hvf.x * hz, hvf.y * hz);   // k = 128+2*lane
    rb[256 + lane]   = f2bf(at * invc);                 // k = 256+lane
    rb[320 + lane]   = f2bf(ae * invc);                 // k = 320+lane
    rb32[192 + lane] = pack2(hvf.x, hvf.y);             // k = 384+2*lane

    // wave-private LDS transpose, then node-major row write (1KB contiguous)
    short8 vv = *(const short8*)(rb + lane * 8);
    *(short8*)(Xb + (size_t)node * 512 + lane * 8) = vv;
  }
}

// ---------------- GEMM (100000 x 512) @ W''^T with fused GRU epilogue ----------------
// v6 = v5 structure (1024 thr, sA 64KB staged once, sW 2x32KB dbuf, wave = 2 mtiles
// x 64 cols, 6 ds_read + 8 MFMA per step). Only change: Xb is now NODE-MAJOR, so
// sA staging computes the A-fragment reorder via per-lane global source addresses
// (global_load_lds: LDS dest linear, global src per-lane).
__global__ __launch_bounds__(1024, 4) void gemm_gru_kernel(
    const unsigned short* __restrict__ Xb,
    const unsigned short* __restrict__ Wb,
    const float* __restrict__ bb,
    const float* __restrict__ sj_r,
    const float* __restrict__ sj,
    float* __restrict__ out) {
  __shared__ __align__(16) unsigned short sA[32768];      // 64 KB: [mt][kt][512]
  __shared__ __align__(16) unsigned short sW[2][16384];   // 2 x 32 KB: [tt][512]
  int wid = threadIdx.x >> 6, lane = threadIdx.x & 63;
  int mg = wid >> 3, cg = wid & 7;
  int mbase = blockIdx.x * 4;
  int col16 = lane & 15, quad = lane >> 4;

  f32x4 acc[2][4];
#pragma unroll
  for (int mi = 0; mi < 2; ++mi)
#pragma unroll
    for (int g = 0; g < 4; ++g) acc[mi][g] = (f32x4)0.0f;

  // ---- prologue staging ----
  // sA: 64 slices (mt 0..3 x kt 0..15), 4 per wave; fragment reorder from
  // node-major Xb: slice u, lane (q=lane>>4, m=lane&15) <- X[mt*16+m][kt*32+q*8]
#pragma unroll
  for (int i = 0; i < 4; ++i) {
    int u = wid * 4 + i;                       // 0..63
    int mt = mbase + (u >> 4);
    if (mt >= MTILES) mt = MTILES - 1;
    const unsigned short* gp = Xb + (size_t)(mt * 16 + (lane & 15)) * 512
                                  + (u & 15) * 32 + (lane >> 4) * 8;
    gload_lds16(gp, sA + u * 512);
  }
  // sW[0]: kt=0 slice, 32 slices (tt 0..31), 2 per wave
#pragma unroll
  for (int i = 0; i < 2; ++i) {
    int tt = wid * 2 + i;                      // 0..31
    const unsigned short* gp = Wb + ((size_t)(tt * 16 + 0) * 64 + lane) * 8;
    gload_lds16(gp, sW[0] + tt * 512);
  }
  __syncthreads();

  const unsigned short* aBase = sA + (size_t)(mg * 32) * 512 + lane * 8;

  for (int kt = 0; kt < 16; ++kt) {
    int cur = kt & 1;
    if (kt < 15) {
#pragma unroll
      for (int i = 0; i < 2; ++i) {
        int tt = wid * 2 + i;
        const unsigned short* gp = Wb + ((size_t)(tt * 16 + kt + 1) * 64 + lane) * 8;
        gload_lds16(gp, sW[cur ^ 1] + tt * 512);
      }
    }
    short8 a0 = *(const short8*)(aBase + (size_t)kt * 512);
    short8 a1 = *(const short8*)(aBase + (size_t)(16 + kt) * 512);
    short8 b0 = *(const short8*)(sW[cur] + (0 * 8 + cg) * 512 + lane * 8);
    short8 b1 = *(const short8*)(sW[cur] + (1 * 8 + cg) * 512 + lane * 8);
    short8 b2 = *(const short8*)(sW[cur] + (2 * 8 + cg) * 512 + lane * 8);
    short8 b3 = *(const short8*)(sW[cur] + (3 * 8 + cg) * 512 + lane * 8);
    acc[0][0] = __builtin_amdgcn_mfma_f32_16x16x32_bf16(a0, b0, acc[0][0], 0, 0, 0);
    acc[0][1] = __builtin_amdgcn_mfma_f32_16x16x32_bf16(a0, b1, acc[0][1], 0, 0, 0);
    acc[0][2] = __builtin_amdgcn_mfma_f32_16x16x32_bf16(a0, b2, acc[0][2], 0, 0, 0);
    acc[0][3] = __builtin_amdgcn_mfma_f32_16x16x32_bf16(a0, b3, acc[0][3], 0, 0, 0);
    acc[1][0] = __builtin_amdgcn_mfma_f32_16x16x32_bf16(a1, b0, acc[1][0], 0, 0, 0);
    acc[1][1] = __builtin_amdgcn_mfma_f32_16x16x32_bf16(a1, b1, acc[1][1], 0, 0, 0);
    acc[1][2] = __builtin_amdgcn_mfma_f32_16x16x32_bf16(a1, b2, acc[1][2], 0, 0, 0);
    acc[1][3] = __builtin_amdgcn_mfma_f32_16x16x32_bf16(a1, b3, acc[1][3], 0, 0, 0);
    __syncthreads();
  }

  // fused GRU epilogue: wave owns out cols [cg*16, cg*16+16), rows = its 2 mtiles
  int cc = cg * 16 + col16;
  float bbr = bb[cc], bbz = bb[128 + cc], bbn = bb[256 + cc], bbh = bb[384 + cc];
#pragma unroll
  for (int mi = 0; mi < 2; ++mi) {
    int mt = mbase + mg * 2 + mi;
    if (mt >= MTILES) continue;
#pragma unroll
    for (int r = 0; r < 4; ++r) {
      int row = mt * 16 + quad * 4 + r;
      float rp  = acc[mi][0][r] + bbr;
      float zp  = acc[mi][1][r] + bbz;
      float inp = acc[mi][2][r] + bbn;
      float hnp = acc[mi][3][r] + bbh;
      float rg = 1.0f / (1.0f + __expf(-rp));
      float zg = 1.0f / (1.0f + __expf(-zp));
      float ng = tanhf(inp + rg * hnp);
      float hv = (row < NUSERS) ? sj_r[(size_t)row * 128 + cc]
                                : sj[(size_t)(row - NUSERS) * 128 + cc];
      out[(size_t)row * 128 + cc] = (1.0f - zg) * ng + zg * hv;
    }
  }
}

extern "C" void kernel_launch(void* const* d_in, const int* in_sizes, int n_in,
                              void* d_out, int out_size, void* d_ws, size_t ws_size,
                              hipStream_t stream) {
  const float* si   = (const float*)d_in[0];
  const float* sj   = (const float*)d_in[1];
  const float* si_r = (const float*)d_in[2];
  const float* sj_r = (const float*)d_in[3];
  const float* t    = (const float*)d_in[4];
  const float* t_r  = (const float*)d_in[5];
  const float* e    = (const float*)d_in[6];
  const float* e_r  = (const float*)d_in[7];
  const float* w_ih = (const float*)d_in[8];
  const float* w_hh = (const float*)d_in[9];
  const float* b_ih = (const float*)d_in[10];
  const float* b_hh = (const float*)d_in[11];
  const int* src_g  = (const int*)d_in[12];
  const int* dst_g  = (const int*)d_in[13];
  const int* src_gr = (const int*)d_in[14];
  const int* dst_gr = (const int*)d_in[15];
  int E = in_sizes[4];

  // workspace layout (16B-aligned head first)
  unsigned short* Xb = (unsigned short*)d_ws;          // 51,200,000 shorts (102.4 MB), node-major
  unsigned short* Wb = Xb + (size_t)NTOT * 512;        // 262144 shorts
  float* bb   = (float*)(Wb + 262144);                 // 512
  int* deg_j  = (int*)(bb + 512);                      // 50000  (memset target, with deg_i)
  int* deg_i  = deg_j + NNODE;                         // 50000
  int* rs_j   = deg_i + NNODE;                         // 50000
  int* rs_i   = rs_j + NNODE;                          // 50000
  int* cur_j  = rs_i + NNODE;                          // 50000
  int* cur_i  = cur_j + NNODE;                         // 50000
  int* csum   = cur_i + NNODE;                         // 2*NCHUNK
  int* coff   = csum + 2 * NCHUNK;                     // 2*NCHUNK (ends 16B-aligned)
  int4* recP_j = (int4*)(coff + 2 * NCHUNK);           // E int4
  int4* recP_i = recP_j + E;                           // E int4
  unsigned short* si_b  = (unsigned short*)(recP_i + E);  // 6.4M shorts (12.8 MB)
  unsigned short* sir_b = si_b + 6400000;                 // 6.4M shorts (12.8 MB)

  hipMemsetAsync(deg_j, 0, 2 * NNODE * sizeof(int), stream);

  pack_w_kernel<<<(512 * 512) / 256, 256, 0, stream>>>(w_ih, w_hh, b_ih, b_hh, Wb, bb);
  cast_mem_kernel<<<6250, 256, 0, stream>>>(si, si_r, si_b, sir_b);

  int blks2E = (2 * E + 255) / 256;
  hist_kernel<<<blks2E, 256, 0, stream>>>(dst_g, dst_gr, deg_j, deg_i, E);
  chunksum_kernel<<<2 * NCHUNK, 256, 0, stream>>>(deg_j, deg_i, csum);
  chunkscan_kernel<<<2, 256, 0, stream>>>(csum, coff);
  localscan_kernel<<<2 * NCHUNK, 256, 0, stream>>>(deg_j, deg_i, coff, rs_j, cur_j, rs_i, cur_i);
  fill_kernel<<<blks2E, 256, 0, stream>>>(src_g, dst_g, t, src_gr, dst_gr, t_r,
                                          cur_j, cur_i, recP_j, recP_i, E);

  gather_kernel<<<NWAVES / 4, 256, 0, stream>>>(si_b, sir_b, sj, sj_r, e, e_r,
                                                rs_j, rs_i, deg_j, deg_i,
                                                recP_j, recP_i, Xb);

  float* out = (float*)d_out;
  gemm_gru_kernel<<<(MTILES + 3) / 4, 1024, 0, stream>>>(Xb, Wb, bb, sj_r, sj, out);
}